// Round 1
// baseline (258.274 us; speedup 1.0000x reference)
//
#include <hip/hip_runtime.h>

// Problem constants (fixed for this instance)
#define NUM_CLASS 20
#define IGNORE_V 255
#define WW 32
#define HH 256
#define DDEPTH 256
#define NVOX (DDEPTH * HH * WW)   // 2,097,152 voxels

// sum_c |onehot_c(b) - onehot_c(a)|  (IGNORE has all-zero onehot)
__device__ __forceinline__ float fpair(int a, int b) {
    if (a == b) return 0.0f;
    return (a == IGNORE_V || b == IGNORE_V) ? 1.0f : 2.0f;
}

__global__ void pal_init(float* acc) {
    acc[0] = 0.0f;
    acc[1] = 0.0f;
}

__global__ __launch_bounds__(256) void pal_main(
    const float* __restrict__ pred,
    const int*   __restrict__ tgt,
    const float* __restrict__ cw,
    float*       __restrict__ acc)   // acc[0]=num, acc[1]=den
{
    const int gid = blockIdx.x * blockDim.x + threadIdx.x;  // float4 index
    const int v0  = gid * 4;

    // 4 consecutive voxels along W (W=32 divisible by 4 -> never crosses a row)
    int4 t4 = *reinterpret_cast<const int4*>(tgt + v0);
    int t[4] = {t4.x, t4.y, t4.z, t4.w};

    // Online logsumexp over 20 classes for 4 voxels; capture pred[t] on the fly.
    float m[4], s[4], pt[4];
    {
        float4 x = *reinterpret_cast<const float4*>(pred + v0);  // class 0
        float xx[4] = {x.x, x.y, x.z, x.w};
        #pragma unroll
        for (int j = 0; j < 4; j++) {
            m[j] = xx[j];
            s[j] = 1.0f;
            pt[j] = (t[j] == 0) ? xx[j] : 0.0f;
        }
    }
    #pragma unroll
    for (int c = 1; c < NUM_CLASS; c++) {
        float4 x = *reinterpret_cast<const float4*>(pred + (size_t)c * NVOX + v0);
        float xx[4] = {x.x, x.y, x.z, x.w};
        #pragma unroll
        for (int j = 0; j < 4; j++) {
            float nm = fmaxf(m[j], xx[j]);
            s[j] = s[j] * __expf(m[j] - nm) + __expf(xx[j] - nm);
            m[j] = nm;
            if (t[j] == c) pt[j] = xx[j];
        }
    }

    float num = 0.0f, den = 0.0f;
    #pragma unroll
    for (int j = 0; j < 4; j++) {
        const int v = v0 + j;
        const int w = v & (WW - 1);
        const int h = (v >> 5) & (HH - 1);
        const int d = v >> 13;
        float lga = 0.0f;
        // W axis (stride 1)
        {
            int im = v - ((w == 0) ? 0 : 1);
            int ip = v + ((w == WW - 1) ? 0 : 1);
            float sc = (w == 0 || w == WW - 1) ? 1.0f : 0.5f;
            lga += sc * fpair(tgt[im], tgt[ip]);
        }
        // H axis (stride 32)
        {
            int im = v - ((h == 0) ? 0 : WW);
            int ip = v + ((h == HH - 1) ? 0 : WW);
            float sc = (h == 0 || h == HH - 1) ? 1.0f : 0.5f;
            lga += sc * fpair(tgt[im], tgt[ip]);
        }
        // D axis (stride 8192)
        {
            int im = v - ((d == 0) ? 0 : WW * HH);
            int ip = v + ((d == DDEPTH - 1) ? 0 : WW * HH);
            float sc = (d == 0 || d == DDEPTH - 1) ? 1.0f : 0.5f;
            lga += sc * fpair(tgt[im], tgt[ip]);
        }
        const int tj = t[j];
        if (tj != IGNORE_V) {
            float wt  = cw[tj];
            float lse = m[j] + __logf(s[j]);
            num += wt * (lse - pt[j]) * (1.0f + lga);   // -logp_t * w * lga_weight
            den += wt;
        }
    }

    // Wave (64-lane) reduction
    #pragma unroll
    for (int off = 32; off > 0; off >>= 1) {
        num += __shfl_down(num, off);
        den += __shfl_down(den, off);
    }
    __shared__ float sn[4], sd[4];
    const int lane = threadIdx.x & 63;
    const int wid  = threadIdx.x >> 6;
    if (lane == 0) { sn[wid] = num; sd[wid] = den; }
    __syncthreads();
    if (threadIdx.x == 0) {
        float n = sn[0] + sn[1] + sn[2] + sn[3];
        float d2 = sd[0] + sd[1] + sd[2] + sd[3];
        atomicAdd(&acc[0], n);
        atomicAdd(&acc[1], d2);
    }
}

__global__ void pal_final(const float* acc, float* out) {
    out[0] = acc[0] / acc[1];
}

extern "C" void kernel_launch(void* const* d_in, const int* in_sizes, int n_in,
                              void* d_out, int out_size, void* d_ws, size_t ws_size,
                              hipStream_t stream) {
    const float* pred = (const float*)d_in[0];
    const int*   tgt  = (const int*)d_in[1];
    const float* cw   = (const float*)d_in[2];
    float* out = (float*)d_out;
    float* acc = (float*)d_ws;

    pal_init<<<1, 1, 0, stream>>>(acc);
    const int threads = 256;
    const int blocks  = (NVOX / 4) / threads;  // 2048
    pal_main<<<blocks, threads, 0, stream>>>(pred, tgt, cw, acc);
    pal_final<<<1, 1, 0, stream>>>(acc, out);
}